// Round 6
// baseline (311.129 us; speedup 1.0000x reference)
//
#include <hip/hip_runtime.h>
#include <hip/hip_bf16.h>
#include <math.h>

#define BB 2
#define DIMC 256
#define FF 4
#define HH 16
#define WW 16
#define GRP 4
#define CPG 64        // DIM/GROUPS
#define ODIM 128      // OFF_DIMS
#define PQ 1024       // F*H*W
#define PJ 128        // FD*HD*WD
#define NBG 8         // B*GROUPS
#define INNERC 512

typedef short bf16x8 __attribute__((ext_vector_type(8)));
typedef float f32x4 __attribute__((ext_vector_type(4)));
typedef float f32x2 __attribute__((ext_vector_type(2)));

__device__ __forceinline__ unsigned int bfbits(float x) {
    union { float f; unsigned int u; } v; v.f = x;
    unsigned int u = v.u;
    unsigned int r = u + 0x7fffu + ((u >> 16) & 1u);
    return r >> 16;
}

__device__ __forceinline__ unsigned int pack_bf2(f32x2 a) {
    float2 ff = make_float2(a.x, a.y);
    __hip_bfloat162 h2 = __float22bfloat162_rn(ff);
    union { __hip_bfloat162 h; unsigned int u; } c; c.h = h2;
    return c.u;
}

// ---- fused: q = grouped 1x1 conv (LDS-resident) -> depthwise conv + GELU; + W1 pack
__global__ __launch_bounds__(256) void k_qdw(
    const float* __restrict__ x, const float* __restrict__ wq,
    const float* __restrict__ dww, const float* __restrict__ dwb,
    const float* __restrict__ w1,
    float* __restrict__ q, float* __restrict__ act, uint4* __restrict__ wb) {
    if (blockIdx.x >= 256) {
        int t = (blockIdx.x - 256) * 256 + threadIdx.x;
        if (t < 512) {
            int lane = t & 63, nt = (t >> 6) & 3, kc = t >> 8;
            int n = nt * 16 + (lane & 15);
            int kbase = kc * 32 + (lane >> 4) * 8;
            unsigned int pk[4];
            #pragma unroll
            for (int p = 0; p < 4; ++p) {
                unsigned int lo = bfbits(w1[(kbase + 2 * p) * 64 + n]);
                unsigned int hi = bfbits(w1[(kbase + 2 * p + 1) * 64 + n]);
                pk[p] = lo | (hi << 16);
            }
            wb[(kc * 4 + nt) * 64 + lane] = make_uint4(pk[0], pk[1], pk[2], pk[3]);
        }
        return;
    }
    __shared__ float qs[1024 * 4];   // qs[p][k] : 16 KB
    int og = blockIdx.x & 31, bg = blockIdx.x >> 5;
    int b = bg >> 2, g = bg & 3;
    int o0 = og * 4;
    int tid = threadIdx.x;
    const float* xp = x + (size_t)(b * DIMC + g * CPG) * PQ;
    const float* wp = wq + (size_t)(g * ODIM + o0) * CPG;

    float accq[4][4] = {};
    #pragma unroll 4
    for (int i = 0; i < CPG; ++i) {
        float wv[4];
        #pragma unroll
        for (int k = 0; k < 4; ++k) wv[k] = wp[k * CPG + i];
        #pragma unroll
        for (int pi = 0; pi < 4; ++pi) {
            float xv = xp[(size_t)i * PQ + tid + pi * 256];
            #pragma unroll
            for (int k = 0; k < 4; ++k) accq[pi][k] += xv * wv[k];
        }
    }
    #pragma unroll
    for (int pi = 0; pi < 4; ++pi) {
        int p = tid + pi * 256;
        *(float4*)&qs[p * 4] = make_float4(accq[pi][0], accq[pi][1], accq[pi][2], accq[pi][3]);
        #pragma unroll
        for (int k = 0; k < 4; ++k)
            q[(size_t)(bg * ODIM + o0 + k) * PQ + p] = accq[pi][k];
    }
    __syncthreads();

    #pragma unroll
    for (int r = 0; r < 2; ++r) {
        int s = r * 256 + tid;       // 512 units = 128 j x 4 c (c fastest)
        int cl = s & 3, j = s >> 2;
        int c = o0 + cl;
        int xo = j & 7, yo = (j >> 3) & 7, zo = j >> 6;
        const float* wd = dww + c * 64;
        float acc = dwb[c];
        #pragma unroll
        for (int kz = 0; kz < 4; ++kz) {
            int z = 2 * zo - 1 + kz;
            if (z < 0 || z >= FF) continue;
            #pragma unroll
            for (int ky = 0; ky < 4; ++ky) {
                int y = 2 * yo - 1 + ky;
                if (y < 0 || y >= HH) continue;
                #pragma unroll
                for (int kx = 0; kx < 4; ++kx) {
                    int xx = 2 * xo - 1 + kx;
                    if (xx < 0 || xx >= WW) continue;
                    acc += qs[((z * HH + y) * WW + xx) * 4 + cl] * wd[(kz * 4 + ky) * 4 + kx];
                }
            }
        }
        // act layout [bg][j][c] so k_kvf reads are lane-coalesced
        act[((size_t)bg * PJ + j) * ODIM + c] =
            0.5f * acc * (1.0f + erff(acc * 0.70710678118654752f));
    }
}

// ------- fused: offsets (1x1 conv reduce + tanh) -> grid -> trilinear sample -> k/v proj
__global__ __launch_bounds__(128) void k_kvf(
    const float* __restrict__ act, const float* __restrict__ pw,
    const float* __restrict__ x, const float* __restrict__ wk,
    const float* __restrict__ wv, float* __restrict__ gkv,
    float* __restrict__ kk2, float* __restrict__ vvT2) {
    __shared__ float red2[6];
    __shared__ float crd[3];
    __shared__ float kvs[64];
    int blk = blockIdx.x;            // bg*128 + j
    int j = blk & 127, bg = blk >> 7;
    int b = bg >> 2, g = bg & 3;
    int tid = threadIdx.x, w = tid >> 6;

    float val = act[((size_t)bg * PJ + j) * ODIM + tid];   // coalesced row
    float s0 = val * pw[tid];
    float s1 = val * pw[ODIM + tid];
    float s2 = val * pw[2 * ODIM + tid];
    #pragma unroll
    for (int off = 32; off; off >>= 1) {
        s0 += __shfl_xor(s0, off);
        s1 += __shfl_xor(s1, off);
        s2 += __shfl_xor(s2, off);
    }
    if ((tid & 63) == 0) { red2[w * 3] = s0; red2[w * 3 + 1] = s1; red2[w * 3 + 2] = s2; }
    __syncthreads();
    if (tid == 0) {
        s0 = red2[0] + red2[3]; s1 = red2[1] + red2[4]; s2 = red2[2] + red2[5];
        float xo = (float)(j & 7), yo = (float)((j >> 3) & 7), zo = (float)(j >> 6);
        float vf = zo + 2.f * tanhf(s0);
        float vh = yo + 2.f * tanhf(s1);
        float vw = xo + 2.f * tanhf(s2);
        float c0 = 2.f * vf - 1.f;
        float c1 = 2.f * vh / 7.f - 1.f;
        float c2 = 2.f * vw / 7.f - 1.f;
        crd[0] = c0; crd[1] = c1; crd[2] = c2;
        gkv[blk * 3 + 0] = c0; gkv[blk * 3 + 1] = c1; gkv[blk * 3 + 2] = c2;
    }
    __syncthreads();

    // BUG-COMPATIBLE: crd[0] (f-coord) -> x/W axis, crd[1] -> y/H, crd[2] (w) -> z/D.
    if (tid < 64) {
        float ix = ((crd[0] + 1.f) * WW - 1.f) * 0.5f;
        float iy = ((crd[1] + 1.f) * HH - 1.f) * 0.5f;
        float iz = ((crd[2] + 1.f) * FF - 1.f) * 0.5f;
        float x0f = floorf(ix), y0f = floorf(iy), z0f = floorf(iz);
        float tx = ix - x0f, ty = iy - y0f, tz = iz - z0f;
        int x0 = (int)x0f, y0 = (int)y0f, z0 = (int)z0f;
        const float* vol = x + (size_t)(b * DIMC + g * CPG + tid) * PQ;
        float acc = 0.f;
        #pragma unroll
        for (int dz = 0; dz < 2; ++dz) {
            int zc = z0 + dz;
            if (zc < 0 || zc >= FF) continue;
            float wz = dz ? tz : 1.f - tz;
            #pragma unroll
            for (int dy = 0; dy < 2; ++dy) {
                int yc = y0 + dy;
                if (yc < 0 || yc >= HH) continue;
                float wy = dy ? ty : 1.f - ty;
                #pragma unroll
                for (int dx = 0; dx < 2; ++dx) {
                    int xc = x0 + dx;
                    if (xc < 0 || xc >= WW) continue;
                    float wgt = wz * wy * (dx ? tx : 1.f - tx);
                    acc += vol[(zc * HH + yc) * WW + xc] * wgt;
                }
            }
        }
        kvs[tid] = acc;
    }
    __syncthreads();

    const float* wkp = wk + (size_t)(g * ODIM + tid) * CPG;
    const float* wvp = wv + (size_t)(g * ODIM + tid) * CPG;
    float ak = 0.f, av = 0.f;
    #pragma unroll
    for (int i = 0; i < 64; i += 4) {
        float4 kv4 = *(const float4*)&kvs[i];
        float4 wk4 = *(const float4*)&wkp[i];
        float4 wv4 = *(const float4*)&wvp[i];
        ak += kv4.x * wk4.x + kv4.y * wk4.y + kv4.z * wk4.z + kv4.w * wk4.w;
        av += kv4.x * wv4.x + kv4.y * wv4.y + kv4.z * wv4.z + kv4.w * wv4.w;
    }
    kk2[((size_t)(bg * 64 + (tid & 63)) * PJ + j) * 2 + (tid >> 6)] = ak;
    vvT2[((size_t)(bg * 64 + (j >> 1)) * ODIM + tid) * 2 + (j & 1)] = av;
}

// ---- CPB bias table: bias[bg][i][j][2], MFMA layer-1, wave-private transpose epilogue
// block = (bg, 16-i tile), 256 thr; wave w handles i = it*16 + w*4 + ii
__global__ __launch_bounds__(256) void k_cpb(
    const float* __restrict__ gkv, const float* __restrict__ w0,
    const float* __restrict__ b0, const uint4* __restrict__ wb,
    const float* __restrict__ b1, const float* __restrict__ w2,
    const float* __restrict__ b2, float* __restrict__ bias) {
    // per-wave transpose buffer: 64 rows x 17 f32x2
    __shared__ __align__(16) float tbuf[4 * 2176];   // 34816 B
    int blk = blockIdx.x;            // bg*64 + it
    int it = blk & 63, bg = blk >> 6;
    int tid = threadIdx.x;
    int w = tid >> 6, lane = tid & 63, col = lane & 15, quad = lane >> 4;

    uint4 bfr[2][4];
    #pragma unroll
    for (int kc = 0; kc < 2; ++kc)
        #pragma unroll
        for (int nt = 0; nt < 4; ++nt)
            bfr[kc][nt] = wb[(kc * 4 + nt) * 64 + lane];

    // per-lane key coords for its A-row in each of the 8 M-tiles: j = mtg*16 + col
    float g0r[8], g1r[8], g2r[8];
    #pragma unroll
    for (int mtg = 0; mtg < 8; ++mtg) {
        int jr = mtg * 16 + col;
        g0r[mtg] = gkv[(bg * PJ + jr) * 3 + 0];
        g1r[mtg] = gkv[(bg * PJ + jr) * 3 + 1];
        g2r[mtg] = gkv[(bg * PJ + jr) * 3 + 2];
    }
    float b1v[4]; f32x2 w2v[4];
    #pragma unroll
    for (int nt = 0; nt < 4; ++nt) {
        int jj = nt * 16 + col;
        b1v[nt] = b1[jj];
        w2v[nt] = *(const f32x2*)&w2[jj * 2];
    }
    f32x2 bias_b2 = *(const f32x2*)b2;
    f32x2* mytb = (f32x2*)&tbuf[w * 2176];

    for (int ii = 0; ii < 4; ++ii) {
        int i = it * 16 + w * 4 + ii;
        int wq_ = i & 15, hq = (i >> 4) & 15, fq = i >> 8;
        float cq0 = 2.f * fq / 3.f - 1.f;
        float cq1 = 2.f * hq / 15.f - 1.f;
        float cq2 = 2.f * wq_ / 15.f - 1.f;

        #pragma unroll
        for (int mh = 0; mh < 2; ++mh) {
            float t0[4], t1[4], t2[4];
            #pragma unroll
            for (int mt = 0; mt < 4; ++mt) {
                int mtg = mh * 4 + mt;
                float p0 = cq0 - g0r[mtg];
                float p1 = cq1 - g1r[mtg];
                float p2 = cq2 - g2r[mtg];
                t0[mt] = copysignf(__logf(1.f + fabsf(p0)), p0);
                t1[mt] = copysignf(__logf(1.f + fabsf(p1)), p1);
                t2[mt] = copysignf(__logf(1.f + fabsf(p2)), p2);
            }
            f32x4 acc[4][4] = {};
            #pragma unroll
            for (int kc = 0; kc < 2; ++kc) {
                int d0 = kc * 32 + quad * 8;
                f32x2 w0a[4], w0b[4], w0c[4], b0p[4];
                #pragma unroll
                for (int pr = 0; pr < 4; ++pr) {
                    w0a[pr] = *(const f32x2*)&w0[d0 + 2 * pr];
                    w0b[pr] = *(const f32x2*)&w0[64 + d0 + 2 * pr];
                    w0c[pr] = *(const f32x2*)&w0[128 + d0 + 2 * pr];
                    b0p[pr] = *(const f32x2*)&b0[d0 + 2 * pr];
                }
                #pragma unroll
                for (int mt = 0; mt < 4; ++mt) {
                    unsigned int pk[4];
                    #pragma unroll
                    for (int pr = 0; pr < 4; ++pr) {
                        f32x2 z = b0p[pr];
                        z += t0[mt] * w0a[pr];
                        z += t1[mt] * w0b[pr];
                        z += t2[mt] * w0c[pr];
                        z.x = fmaxf(z.x, 0.f); z.y = fmaxf(z.y, 0.f);
                        pk[pr] = pack_bf2(z);
                    }
                    uint4 afu = make_uint4(pk[0], pk[1], pk[2], pk[3]);
                    bf16x8 af = *(bf16x8*)&afu;
                    #pragma unroll
                    for (int nt = 0; nt < 4; ++nt)
                        acc[mt][nt] = __builtin_amdgcn_mfma_f32_16x16x32_bf16(
                            af, *(bf16x8*)&bfr[kc][nt], acc[mt][nt], 0, 0, 0);
                }
            }
            // epilogue: relu(h1+b1) @ w2 -> wave-private LDS transpose (no barrier)
            #pragma unroll
            for (int mt = 0; mt < 4; ++mt)
                #pragma unroll
                for (int reg = 0; reg < 4; ++reg) {
                    f32x2 pp = {0.f, 0.f};
                    #pragma unroll
                    for (int nt = 0; nt < 4; ++nt) {
                        float hv = fmaxf(acc[mt][nt][reg] + b1v[nt], 0.f);
                        pp += hv * w2v[nt];
                    }
                    mytb[(mt * 16 + quad * 4 + reg) * 17 + col] = pp;
                }
            f32x2 s = bias_b2;
            {
                const f32x2* pr2 = mytb + lane * 17;
                #pragma unroll
                for (int c = 0; c < 16; ++c) s += pr2[c];
            }
            int j = mh * 64 + lane;
            *(f32x2*)(bias + (((size_t)bg * PQ + i) * PJ + j) * 2) = s;
        }
    }
}

// ---- slim attention: bias-read + QK^T + softmax + attn*V, 4 queries/block
__global__ __launch_bounds__(128) void k_attn(
    const float* __restrict__ q, const float* __restrict__ kk2,
    const float* __restrict__ vvT2, const float* __restrict__ bias,
    float* __restrict__ outh) {
    __shared__ float qsL[512];       // [ii][d*2+e]
    __shared__ float attL[1024];     // [ii][head][j]
    __shared__ float redA[16];

    int blk = blockIdx.x;            // bg*256 + it
    int it = blk & 255, bg = blk >> 8;
    int i0 = it * 4;
    int b = bg >> 2, g = bg & 3;
    int tid = threadIdx.x;
    int w = tid >> 6, lane = tid & 63;
    int j = tid;

    {
        float4 q4 = *(const float4*)(q + (size_t)(bg * ODIM + tid) * PQ + i0);
        int e = tid >> 6, d = tid & 63;
        qsL[0 * 128 + d * 2 + e] = q4.x * 0.125f;
        qsL[1 * 128 + d * 2 + e] = q4.y * 0.125f;
        qsL[2 * 128 + d * 2 + e] = q4.z * 0.125f;
        qsL[3 * 128 + d * 2 + e] = q4.w * 0.125f;
    }
    __syncthreads();

    f32x2 sc[4];
    #pragma unroll
    for (int ii = 0; ii < 4; ++ii)
        sc[ii] = *(const f32x2*)(bias + (((size_t)bg * PQ + i0 + ii) * PJ + j) * 2);

    {
        const f32x2* kp = (const f32x2*)kk2 + (size_t)(bg * 64) * PJ + j;
        #pragma unroll 4
        for (int d = 0; d < 64; ++d) {
            f32x2 kv2 = kp[(size_t)d * PJ];
            #pragma unroll
            for (int ii = 0; ii < 4; ++ii) {
                f32x2 qv = *(const f32x2*)&qsL[ii * 128 + d * 2];
                sc[ii] += qv * kv2;
            }
        }
    }
    #pragma unroll
    for (int ii = 0; ii < 4; ++ii) {
        attL[ii * 256 + j] = sc[ii].x;
        attL[ii * 256 + 128 + j] = sc[ii].y;
    }
    __syncthreads();

    #pragma unroll
    for (int ii = 0; ii < 4; ++ii) {
        float a0 = attL[ii * 256 + w * 128 + lane];
        float a1 = attL[ii * 256 + w * 128 + 64 + lane];
        float mx = fmaxf(a0, a1);
        #pragma unroll
        for (int off = 32; off; off >>= 1) mx = fmaxf(mx, __shfl_xor(mx, off));
        float ex = __expf(a0 - mx) + __expf(a1 - mx);
        #pragma unroll
        for (int off = 32; off; off >>= 1) ex += __shfl_xor(ex, off);
        if (lane == 0) { redA[ii * 4 + w * 2] = mx; redA[ii * 4 + w * 2 + 1] = ex; }
    }
    __syncthreads();
    #pragma unroll
    for (int ii = 0; ii < 4; ++ii) {
        float p0n = __expf(sc[ii].x - redA[ii * 4 + 0]) * (1.f / redA[ii * 4 + 1]);
        float p1n = __expf(sc[ii].y - redA[ii * 4 + 2]) * (1.f / redA[ii * 4 + 3]);
        attL[ii * 256 + j] = p0n;
        attL[ii * 256 + 128 + j] = p1n;
    }
    __syncthreads();

    {
        const f32x2* vp = (const f32x2*)vvT2 + (size_t)(bg * 64) * ODIM + tid;
        f32x2 oacc[4] = {};
        #pragma unroll 4
        for (int jp = 0; jp < 64; ++jp) {
            f32x2 vv2 = vp[(size_t)jp * ODIM];
            #pragma unroll
            for (int ii = 0; ii < 4; ++ii) {
                f32x2 ap2 = *(const f32x2*)&attL[ii * 256 + w * 128 + jp * 2];
                oacc[ii] += ap2 * vv2;
            }
        }
        #pragma unroll
        for (int ii = 0; ii < 4; ++ii)
            outh[((size_t)b * PQ + i0 + ii) * INNERC + g * 128 + tid] =
                oacc[ii].x + oacc[ii].y;
    }
}

// ---------------- final projection: 2048 blocks, one (o,p) dot per thread --------
__global__ __launch_bounds__(256) void k_out(
    const float* __restrict__ outh, const float* __restrict__ wo,
    const float* __restrict__ bo, float* __restrict__ out) {
    int blk = blockIdx.x;            // b*1024 + og*32 + pt
    int pt = blk & 31, og = (blk >> 5) & 31, b = blk >> 10;
    int tid = threadIdx.x;
    int ol = tid & 7, pl = tid >> 3;
    int o = og * 8 + ol, p = pt * 32 + pl;
    const float* hp = outh + ((size_t)b * PQ + p) * INNERC;
    const float* wp = wo + (size_t)o * INNERC;
    float acc = bo[o];
    #pragma unroll 8
    for (int c = 0; c < INNERC; c += 4) {
        float4 hv = *(const float4*)&hp[c];
        float4 wr = *(const float4*)&wp[c];
        acc += hv.x * wr.x + hv.y * wr.y + hv.z * wr.z + hv.w * wr.w;
    }
    out[(size_t)(b * DIMC + o) * PQ + p] = acc;
}

extern "C" void kernel_launch(void* const* d_in, const int* in_sizes, int n_in,
                              void* d_out, int out_size, void* d_ws, size_t ws_size,
                              hipStream_t stream) {
    const float* x   = (const float*)d_in[0];
    const float* wq  = (const float*)d_in[1];
    const float* wk  = (const float*)d_in[2];
    const float* wv  = (const float*)d_in[3];
    const float* dww = (const float*)d_in[4];
    const float* dwb = (const float*)d_in[5];
    const float* pw  = (const float*)d_in[6];
    const float* w0  = (const float*)d_in[7];
    const float* b0  = (const float*)d_in[8];
    const float* w1  = (const float*)d_in[9];
    const float* b1  = (const float*)d_in[10];
    const float* w2  = (const float*)d_in[11];
    const float* b2  = (const float*)d_in[12];
    const float* wo  = (const float*)d_in[13];
    const float* bo  = (const float*)d_in[14];
    float* out = (float*)d_out;

    float* ws_f  = (float*)d_ws;
    uint4* wb    = (uint4*)ws_f;          // 2048 floats
    float* q     = ws_f + 2048;           // 1048576
    float* act   = q + 1048576;           // 131072
    float* gkv   = act + 131072;          // 3072
    float* kk2   = gkv + 3072;            // 131072
    float* vvT2  = kk2 + 131072;          // 131072
    float* outh  = vvT2 + 131072;         // 1048576
    float* biasT = outh + 1048576;        // 8*1024*128*2 = 2097152

    k_qdw<<<258, 256, 0, stream>>>(x, wq, dww, dwb, w1, q, act, wb);
    k_kvf<<<1024, 128, 0, stream>>>(act, pw, x, wk, wv, gkv, kk2, vvT2);
    k_cpb<<<512, 256, 0, stream>>>(gkv, w0, b0, wb, b1, w2, b2, biasT);
    k_attn<<<2048, 128, 0, stream>>>(q, kk2, vvT2, biasT, outh);
    k_out<<<2048, 256, 0, stream>>>(outh, wo, bo, out);
}

// Round 8
// 184.920 us; speedup vs baseline: 1.6825x; 1.6825x over previous
//
#include <hip/hip_runtime.h>
#include <hip/hip_bf16.h>
#include <math.h>

#define BB 2
#define DIMC 256
#define FF 4
#define HH 16
#define WW 16
#define GRP 4
#define CPG 64        // DIM/GROUPS
#define ODIM 128      // OFF_DIMS
#define PQ 1024       // F*H*W
#define PJ 128        // FD*HD*WD
#define NBG 8         // B*GROUPS
#define INNERC 512

typedef short bf16x8 __attribute__((ext_vector_type(8)));
typedef float f32x4 __attribute__((ext_vector_type(4)));
typedef float f32x2 __attribute__((ext_vector_type(2)));

__device__ __forceinline__ unsigned int bfbits(float x) {
    union { float f; unsigned int u; } v; v.f = x;
    unsigned int u = v.u;
    unsigned int r = u + 0x7fffu + ((u >> 16) & 1u);
    return r >> 16;
}

__device__ __forceinline__ unsigned int pack_bf2(f32x2 a) {
    float2 ff = make_float2(a.x, a.y);
    __hip_bfloat162 h2 = __float22bfloat162_rn(ff);
    union { __hip_bfloat162 h; unsigned int u; } c; c.h = h2;
    return c.u;
}

// ---- fused: q = grouped 1x1 conv (LDS-resident) -> depthwise conv + GELU; + W1 pack
__global__ __launch_bounds__(256) void k_qdw(
    const float* __restrict__ x, const float* __restrict__ wq,
    const float* __restrict__ dww, const float* __restrict__ dwb,
    const float* __restrict__ w1,
    float* __restrict__ q, float* __restrict__ act, uint4* __restrict__ wb) {
    if (blockIdx.x >= 256) {
        int t = (blockIdx.x - 256) * 256 + threadIdx.x;
        if (t < 512) {
            int lane = t & 63, nt = (t >> 6) & 3, kc = t >> 8;
            int n = nt * 16 + (lane & 15);
            int kbase = kc * 32 + (lane >> 4) * 8;
            unsigned int pk[4];
            #pragma unroll
            for (int p = 0; p < 4; ++p) {
                unsigned int lo = bfbits(w1[(kbase + 2 * p) * 64 + n]);
                unsigned int hi = bfbits(w1[(kbase + 2 * p + 1) * 64 + n]);
                pk[p] = lo | (hi << 16);
            }
            wb[(kc * 4 + nt) * 64 + lane] = make_uint4(pk[0], pk[1], pk[2], pk[3]);
        }
        return;
    }
    __shared__ float qs[1024 * 4];   // qs[p][k] : 16 KB
    int og = blockIdx.x & 31, bg = blockIdx.x >> 5;
    int b = bg >> 2, g = bg & 3;
    int o0 = og * 4;
    int tid = threadIdx.x;
    const float* xp = x + (size_t)(b * DIMC + g * CPG) * PQ;
    const float* wp = wq + (size_t)(g * ODIM + o0) * CPG;

    float accq[4][4] = {};
    #pragma unroll 4
    for (int i = 0; i < CPG; ++i) {
        float wv[4];
        #pragma unroll
        for (int k = 0; k < 4; ++k) wv[k] = wp[k * CPG + i];
        #pragma unroll
        for (int pi = 0; pi < 4; ++pi) {
            float xv = xp[(size_t)i * PQ + tid + pi * 256];
            #pragma unroll
            for (int k = 0; k < 4; ++k) accq[pi][k] += xv * wv[k];
        }
    }
    #pragma unroll
    for (int pi = 0; pi < 4; ++pi) {
        int p = tid + pi * 256;
        *(float4*)&qs[p * 4] = make_float4(accq[pi][0], accq[pi][1], accq[pi][2], accq[pi][3]);
        #pragma unroll
        for (int k = 0; k < 4; ++k)
            q[(size_t)(bg * ODIM + o0 + k) * PQ + p] = accq[pi][k];
    }
    __syncthreads();

    #pragma unroll
    for (int r = 0; r < 2; ++r) {
        int s = r * 256 + tid;       // 512 units = 128 j x 4 c (c fastest)
        int cl = s & 3, j = s >> 2;
        int c = o0 + cl;
        int xo = j & 7, yo = (j >> 3) & 7, zo = j >> 6;
        const float* wd = dww + c * 64;
        float acc = dwb[c];
        #pragma unroll
        for (int kz = 0; kz < 4; ++kz) {
            int z = 2 * zo - 1 + kz;
            if (z < 0 || z >= FF) continue;
            #pragma unroll
            for (int ky = 0; ky < 4; ++ky) {
                int y = 2 * yo - 1 + ky;
                if (y < 0 || y >= HH) continue;
                #pragma unroll
                for (int kx = 0; kx < 4; ++kx) {
                    int xx = 2 * xo - 1 + kx;
                    if (xx < 0 || xx >= WW) continue;
                    acc += qs[((z * HH + y) * WW + xx) * 4 + cl] * wd[(kz * 4 + ky) * 4 + kx];
                }
            }
        }
        act[((size_t)bg * PJ + j) * ODIM + c] =
            0.5f * acc * (1.0f + erff(acc * 0.70710678118654752f));
    }
}

// ------- fused: offsets (1x1 conv reduce + tanh) -> grid -> trilinear sample -> k/v proj
__global__ __launch_bounds__(128) void k_kvf(
    const float* __restrict__ act, const float* __restrict__ pw,
    const float* __restrict__ x, const float* __restrict__ wk,
    const float* __restrict__ wv, float* __restrict__ gkv,
    float* __restrict__ kk2, float* __restrict__ vvT2) {
    __shared__ float red2[6];
    __shared__ float crd[3];
    __shared__ float kvs[64];
    int blk = blockIdx.x;            // bg*128 + j
    int j = blk & 127, bg = blk >> 7;
    int b = bg >> 2, g = bg & 3;
    int tid = threadIdx.x, w = tid >> 6;

    float val = act[((size_t)bg * PJ + j) * ODIM + tid];   // coalesced row
    float s0 = val * pw[tid];
    float s1 = val * pw[ODIM + tid];
    float s2 = val * pw[2 * ODIM + tid];
    #pragma unroll
    for (int off = 32; off; off >>= 1) {
        s0 += __shfl_xor(s0, off);
        s1 += __shfl_xor(s1, off);
        s2 += __shfl_xor(s2, off);
    }
    if ((tid & 63) == 0) { red2[w * 3] = s0; red2[w * 3 + 1] = s1; red2[w * 3 + 2] = s2; }
    __syncthreads();
    if (tid == 0) {
        s0 = red2[0] + red2[3]; s1 = red2[1] + red2[4]; s2 = red2[2] + red2[5];
        float xo = (float)(j & 7), yo = (float)((j >> 3) & 7), zo = (float)(j >> 6);
        float vf = zo + 2.f * tanhf(s0);
        float vh = yo + 2.f * tanhf(s1);
        float vw = xo + 2.f * tanhf(s2);
        float c0 = 2.f * vf - 1.f;
        float c1 = 2.f * vh / 7.f - 1.f;
        float c2 = 2.f * vw / 7.f - 1.f;
        crd[0] = c0; crd[1] = c1; crd[2] = c2;
        gkv[blk * 3 + 0] = c0; gkv[blk * 3 + 1] = c1; gkv[blk * 3 + 2] = c2;
    }
    __syncthreads();

    // BUG-COMPATIBLE: crd[0] (f-coord) -> x/W axis, crd[1] -> y/H, crd[2] (w) -> z/D.
    if (tid < 64) {
        float ix = ((crd[0] + 1.f) * WW - 1.f) * 0.5f;
        float iy = ((crd[1] + 1.f) * HH - 1.f) * 0.5f;
        float iz = ((crd[2] + 1.f) * FF - 1.f) * 0.5f;
        float x0f = floorf(ix), y0f = floorf(iy), z0f = floorf(iz);
        float tx = ix - x0f, ty = iy - y0f, tz = iz - z0f;
        int x0 = (int)x0f, y0 = (int)y0f, z0 = (int)z0f;
        const float* vol = x + (size_t)(b * DIMC + g * CPG + tid) * PQ;
        float acc = 0.f;
        #pragma unroll
        for (int dz = 0; dz < 2; ++dz) {
            int zc = z0 + dz;
            if (zc < 0 || zc >= FF) continue;
            float wz = dz ? tz : 1.f - tz;
            #pragma unroll
            for (int dy = 0; dy < 2; ++dy) {
                int yc = y0 + dy;
                if (yc < 0 || yc >= HH) continue;
                float wy = dy ? ty : 1.f - ty;
                #pragma unroll
                for (int dx = 0; dx < 2; ++dx) {
                    int xc = x0 + dx;
                    if (xc < 0 || xc >= WW) continue;
                    float wgt = wz * wy * (dx ? tx : 1.f - tx);
                    acc += vol[(zc * HH + yc) * WW + xc] * wgt;
                }
            }
        }
        kvs[tid] = acc;
    }
    __syncthreads();

    const float* wkp = wk + (size_t)(g * ODIM + tid) * CPG;
    const float* wvp = wv + (size_t)(g * ODIM + tid) * CPG;
    float ak = 0.f, av = 0.f;
    #pragma unroll
    for (int i = 0; i < 64; i += 4) {
        float4 kv4 = *(const float4*)&kvs[i];
        float4 wk4 = *(const float4*)&wkp[i];
        float4 wv4 = *(const float4*)&wvp[i];
        ak += kv4.x * wk4.x + kv4.y * wk4.y + kv4.z * wk4.z + kv4.w * wk4.w;
        av += kv4.x * wv4.x + kv4.y * wv4.y + kv4.z * wv4.z + kv4.w * wv4.w;
    }
    kk2[((size_t)(bg * 64 + (tid & 63)) * PJ + j) * 2 + (tid >> 6)] = ak;
    vvT2[((size_t)(bg * 64 + (j >> 1)) * ODIM + tid) * 2 + (j & 1)] = av;
}

// ---- CPB bias table: bias[bg][i][j][2], MFMA layer-1, wave-private transpose epilogue
__global__ __launch_bounds__(256) void k_cpb(
    const float* __restrict__ gkv, const float* __restrict__ w0,
    const float* __restrict__ b0, const uint4* __restrict__ wb,
    const float* __restrict__ b1, const float* __restrict__ w2,
    const float* __restrict__ b2, float* __restrict__ bias) {
    __shared__ __align__(16) float tbuf[4 * 2176];   // 34816 B
    int blk = blockIdx.x;            // bg*64 + it
    int it = blk & 63, bg = blk >> 6;
    int tid = threadIdx.x;
    int w = tid >> 6, lane = tid & 63, col = lane & 15, quad = lane >> 4;

    uint4 bfr[2][4];
    #pragma unroll
    for (int kc = 0; kc < 2; ++kc)
        #pragma unroll
        for (int nt = 0; nt < 4; ++nt)
            bfr[kc][nt] = wb[(kc * 4 + nt) * 64 + lane];

    float g0r[8], g1r[8], g2r[8];
    #pragma unroll
    for (int mtg = 0; mtg < 8; ++mtg) {
        int jr = mtg * 16 + col;
        g0r[mtg] = gkv[(bg * PJ + jr) * 3 + 0];
        g1r[mtg] = gkv[(bg * PJ + jr) * 3 + 1];
        g2r[mtg] = gkv[(bg * PJ + jr) * 3 + 2];
    }
    float b1v[4]; f32x2 w2v[4];
    #pragma unroll
    for (int nt = 0; nt < 4; ++nt) {
        int jj = nt * 16 + col;
        b1v[nt] = b1[jj];
        w2v[nt] = *(const f32x2*)&w2[jj * 2];
    }
    f32x2 bias_b2 = *(const f32x2*)b2;
    f32x2* mytb = (f32x2*)&tbuf[w * 2176];

    for (int ii = 0; ii < 4; ++ii) {
        int i = it * 16 + w * 4 + ii;
        int wq_ = i & 15, hq = (i >> 4) & 15, fq = i >> 8;
        float cq0 = 2.f * fq / 3.f - 1.f;
        float cq1 = 2.f * hq / 15.f - 1.f;
        float cq2 = 2.f * wq_ / 15.f - 1.f;

        #pragma unroll
        for (int mh = 0; mh < 2; ++mh) {
            float t0[4], t1[4], t2[4];
            #pragma unroll
            for (int mt = 0; mt < 4; ++mt) {
                int mtg = mh * 4 + mt;
                float p0 = cq0 - g0r[mtg];
                float p1 = cq1 - g1r[mtg];
                float p2 = cq2 - g2r[mtg];
                t0[mt] = copysignf(__logf(1.f + fabsf(p0)), p0);
                t1[mt] = copysignf(__logf(1.f + fabsf(p1)), p1);
                t2[mt] = copysignf(__logf(1.f + fabsf(p2)), p2);
            }
            f32x4 acc[4][4] = {};
            #pragma unroll
            for (int kc = 0; kc < 2; ++kc) {
                int d0 = kc * 32 + quad * 8;
                f32x2 w0a[4], w0b[4], w0c[4], b0p[4];
                #pragma unroll
                for (int pr = 0; pr < 4; ++pr) {
                    w0a[pr] = *(const f32x2*)&w0[d0 + 2 * pr];
                    w0b[pr] = *(const f32x2*)&w0[64 + d0 + 2 * pr];
                    w0c[pr] = *(const f32x2*)&w0[128 + d0 + 2 * pr];
                    b0p[pr] = *(const f32x2*)&b0[d0 + 2 * pr];
                }
                #pragma unroll
                for (int mt = 0; mt < 4; ++mt) {
                    unsigned int pk[4];
                    #pragma unroll
                    for (int pr = 0; pr < 4; ++pr) {
                        f32x2 z = b0p[pr];
                        z += t0[mt] * w0a[pr];
                        z += t1[mt] * w0b[pr];
                        z += t2[mt] * w0c[pr];
                        z.x = fmaxf(z.x, 0.f); z.y = fmaxf(z.y, 0.f);
                        pk[pr] = pack_bf2(z);
                    }
                    uint4 afu = make_uint4(pk[0], pk[1], pk[2], pk[3]);
                    bf16x8 af = *(bf16x8*)&afu;
                    #pragma unroll
                    for (int nt = 0; nt < 4; ++nt)
                        acc[mt][nt] = __builtin_amdgcn_mfma_f32_16x16x32_bf16(
                            af, *(bf16x8*)&bfr[kc][nt], acc[mt][nt], 0, 0, 0);
                }
            }
            #pragma unroll
            for (int mt = 0; mt < 4; ++mt)
                #pragma unroll
                for (int reg = 0; reg < 4; ++reg) {
                    f32x2 pp = {0.f, 0.f};
                    #pragma unroll
                    for (int nt = 0; nt < 4; ++nt) {
                        float hv = fmaxf(acc[mt][nt][reg] + b1v[nt], 0.f);
                        pp += hv * w2v[nt];
                    }
                    mytb[(mt * 16 + quad * 4 + reg) * 17 + col] = pp;
                }
            f32x2 s = bias_b2;
            {
                const f32x2* pr2 = mytb + lane * 17;
                #pragma unroll
                for (int c = 0; c < 16; ++c) s += pr2[c];
            }
            int j = mh * 64 + lane;
            *(f32x2*)(bias + (((size_t)bg * PQ + i) * PJ + j) * 2) = s;
        }
    }
}

// ---- slim attention: bias-read + QK^T + softmax + attn*V, 4 queries/block
__global__ __launch_bounds__(128) void k_attn(
    const float* __restrict__ q, const float* __restrict__ kk2,
    const float* __restrict__ vvT2, const float* __restrict__ bias,
    float* __restrict__ outh) {
    __shared__ float qsL[512];       // [ii][d*2+e]
    __shared__ float attL[1024];     // [ii][head][j]
    __shared__ float redA[16];

    int blk = blockIdx.x;            // bg*256 + it
    int it = blk & 255, bg = blk >> 8;
    int i0 = it * 4;
    int b = bg >> 2, g = bg & 3;
    int tid = threadIdx.x;
    int w = tid >> 6, lane = tid & 63;
    int j = tid;

    {
        float4 q4 = *(const float4*)(q + (size_t)(bg * ODIM + tid) * PQ + i0);
        int e = tid >> 6, d = tid & 63;
        qsL[0 * 128 + d * 2 + e] = q4.x * 0.125f;
        qsL[1 * 128 + d * 2 + e] = q4.y * 0.125f;
        qsL[2 * 128 + d * 2 + e] = q4.z * 0.125f;
        qsL[3 * 128 + d * 2 + e] = q4.w * 0.125f;
    }
    __syncthreads();

    f32x2 sc[4];
    #pragma unroll
    for (int ii = 0; ii < 4; ++ii)
        sc[ii] = *(const f32x2*)(bias + (((size_t)bg * PQ + i0 + ii) * PJ + j) * 2);

    {
        const f32x2* kp = (const f32x2*)kk2 + (size_t)(bg * 64) * PJ + j;
        #pragma unroll 4
        for (int d = 0; d < 64; ++d) {
            f32x2 kv2 = kp[(size_t)d * PJ];
            #pragma unroll
            for (int ii = 0; ii < 4; ++ii) {
                f32x2 qv = *(const f32x2*)&qsL[ii * 128 + d * 2];
                sc[ii] += qv * kv2;
            }
        }
    }
    #pragma unroll
    for (int ii = 0; ii < 4; ++ii) {
        attL[ii * 256 + j] = sc[ii].x;
        attL[ii * 256 + 128 + j] = sc[ii].y;
    }
    __syncthreads();

    #pragma unroll
    for (int ii = 0; ii < 4; ++ii) {
        float a0 = attL[ii * 256 + w * 128 + lane];
        float a1 = attL[ii * 256 + w * 128 + 64 + lane];
        float mx = fmaxf(a0, a1);
        #pragma unroll
        for (int off = 32; off; off >>= 1) mx = fmaxf(mx, __shfl_xor(mx, off));
        float ex = __expf(a0 - mx) + __expf(a1 - mx);
        #pragma unroll
        for (int off = 32; off; off >>= 1) ex += __shfl_xor(ex, off);
        if (lane == 0) { redA[ii * 4 + w * 2] = mx; redA[ii * 4 + w * 2 + 1] = ex; }
    }
    __syncthreads();
    #pragma unroll
    for (int ii = 0; ii < 4; ++ii) {
        float p0n = __expf(sc[ii].x - redA[ii * 4 + 0]) * (1.f / redA[ii * 4 + 1]);
        float p1n = __expf(sc[ii].y - redA[ii * 4 + 2]) * (1.f / redA[ii * 4 + 3]);
        attL[ii * 256 + j] = p0n;
        attL[ii * 256 + 128 + j] = p1n;
    }
    __syncthreads();

    {
        const f32x2* vp = (const f32x2*)vvT2 + (size_t)(bg * 64) * ODIM + tid;
        f32x2 oacc[4] = {};
        #pragma unroll 4
        for (int jp = 0; jp < 64; ++jp) {
            f32x2 vv2 = vp[(size_t)jp * ODIM];
            #pragma unroll
            for (int ii = 0; ii < 4; ++ii) {
                f32x2 ap2 = *(const f32x2*)&attL[ii * 256 + w * 128 + jp * 2];
                oacc[ii] += ap2 * vv2;
            }
        }
        #pragma unroll
        for (int ii = 0; ii < 4; ++ii)
            outh[((size_t)b * PQ + i0 + ii) * INNERC + g * 128 + tid] =
                oacc[ii].x + oacc[ii].y;
    }
}

// ---- final projection: LDS-tiled fp32 GEMM. M=2048 (b*p), N=256 (o), K=512.
// tile 64(M) x 32(N), K-chunk 32; grid 32x8 = 256 blocks; 8 acc/thread (4m x 2n)
// LDS row strides: At 68 floats (272 B, 16B-mult), Bt 36 floats (144 B) -> aligned vec reads
__global__ __launch_bounds__(256) void k_out(
    const float* __restrict__ outh, const float* __restrict__ wo,
    const float* __restrict__ bo, float* __restrict__ out) {
    __shared__ float At[32][68];
    __shared__ float Bt[32][36];
    int blk = blockIdx.x;            // 0..255
    int nt = blk & 7, mt = blk >> 3;
    int m0 = mt * 64, o0 = nt * 32;
    int tid = threadIdx.x;
    int tm = tid >> 4, tn = tid & 15;           // 16 x 16 thread grid
    int mloc = tm * 4, nloc = tn * 2;

    int ra = tid >> 2, ca = (tid & 3) * 8;      // A: 64 rows x 32 c, 2 float4/thread
    int rb = tid >> 3, cb = (tid & 7) * 4;      // B: 32 rows x 32 c, 1 float4/thread

    float4 pa0, pa1, pb;
    {
        const float* Ap = outh + (size_t)(m0 + ra) * INNERC + ca;
        pa0 = *(const float4*)Ap;
        pa1 = *(const float4*)(Ap + 4);
        pb = *(const float4*)(wo + (size_t)(o0 + rb) * INNERC + cb);
    }

    float acc[4][2] = {};
    for (int ch = 0; ch < 16; ++ch) {
        #pragma unroll
        for (int k = 0; k < 4; ++k) {
            At[ca + k][ra] = ((const float*)&pa0)[k];
            At[ca + 4 + k][ra] = ((const float*)&pa1)[k];
            Bt[cb + k][rb] = ((const float*)&pb)[k];
        }
        __syncthreads();
        if (ch < 15) {
            int c0 = (ch + 1) * 32;
            const float* Ap = outh + (size_t)(m0 + ra) * INNERC + c0 + ca;
            pa0 = *(const float4*)Ap;
            pa1 = *(const float4*)(Ap + 4);
            pb = *(const float4*)(wo + (size_t)(o0 + rb) * INNERC + c0 + cb);
        }
        #pragma unroll
        for (int kk = 0; kk < 32; ++kk) {
            float4 a4 = *(const float4*)&At[kk][mloc];
            float2 b2 = *(const float2*)&Bt[kk][nloc];
            #pragma unroll
            for (int i = 0; i < 4; ++i) {
                float av = ((const float*)&a4)[i];
                acc[i][0] += av * b2.x;
                acc[i][1] += av * b2.y;
            }
        }
        __syncthreads();
    }

    #pragma unroll
    for (int jn = 0; jn < 2; ++jn) {
        int o = o0 + nloc + jn;
        float bv = bo[o];
        #pragma unroll
        for (int i = 0; i < 4; ++i) {
            int m = m0 + mloc + i;
            int b = m >> 10, p = m & 1023;
            out[((size_t)(b * DIMC + o)) * PQ + p] = acc[i][jn] + bv;
        }
    }
}

extern "C" void kernel_launch(void* const* d_in, const int* in_sizes, int n_in,
                              void* d_out, int out_size, void* d_ws, size_t ws_size,
                              hipStream_t stream) {
    const float* x   = (const float*)d_in[0];
    const float* wq  = (const float*)d_in[1];
    const float* wk  = (const float*)d_in[2];
    const float* wv  = (const float*)d_in[3];
    const float* dww = (const float*)d_in[4];
    const float* dwb = (const float*)d_in[5];
    const float* pw  = (const float*)d_in[6];
    const float* w0  = (const float*)d_in[7];
    const float* b0  = (const float*)d_in[8];
    const float* w1  = (const float*)d_in[9];
    const float* b1  = (const float*)d_in[10];
    const float* w2  = (const float*)d_in[11];
    const float* b2  = (const float*)d_in[12];
    const float* wo  = (const float*)d_in[13];
    const float* bo  = (const float*)d_in[14];
    float* out = (float*)d_out;

    float* ws_f  = (float*)d_ws;
    uint4* wb    = (uint4*)ws_f;          // 2048 floats
    float* q     = ws_f + 2048;           // 1048576
    float* act   = q + 1048576;           // 131072
    float* gkv   = act + 131072;          // 3072
    float* kk2   = gkv + 3072;            // 131072
    float* vvT2  = kk2 + 131072;          // 131072
    float* outh  = vvT2 + 131072;         // 1048576
    float* biasT = outh + 1048576;        // 2097152

    k_qdw<<<258, 256, 0, stream>>>(x, wq, dww, dwb, w1, q, act, wb);
    k_kvf<<<1024, 128, 0, stream>>>(act, pw, x, wk, wv, gkv, kk2, vvT2);
    k_cpb<<<512, 256, 0, stream>>>(gkv, w0, b0, wb, b1, w2, b2, biasT);
    k_attn<<<2048, 128, 0, stream>>>(q, kk2, vvT2, biasT, outh);
    k_out<<<256, 256, 0, stream>>>(outh, wo, bo, out);
}